// Round 1
// baseline (4366.397 us; speedup 1.0000x reference)
//
#include <hip/hip_runtime.h>
#include <math.h>

#define N      100   // nodes per problem
#define D      128   // embedding dim = H*DKH
#define H      8
#define DKH    16
#define KL     10    // prefix length
#define S0     90    // initial unvisited slots
#define STEPS  90
#define LDK    132   // padded LDS row stride (floats), 16B-aligned, +4 rotation
#define NT     512

__device__ __forceinline__ float dot4(float4 a, float4 b) {
  return a.x*b.x + a.y*b.y + a.z*b.z + a.w*b.w;
}

__global__ __launch_bounds__(NT, 2)
void policy_kernel(const float* __restrict__ enc,
                   const float* __restrict__ Wq_first,
                   const float* __restrict__ Wq_last,
                   const float* __restrict__ Wk,
                   const float* __restrict__ Wv,
                   const float* __restrict__ Wcomb,
                   const int*   __restrict__ prefix,
                   int*         __restrict__ out) {
  // ---- LDS (about 155.6 KB of the 160 KB) ----
  __shared__ __align__(16) float sK [S0*LDK];   // K[slot][j], j = h*16+e
  __shared__ __align__(16) float sV [S0*LDK];   // V[slot][j]
  __shared__ __align__(16) float sCE[S0*LDK];   // CE[slot][k] = Wcomb[k,:]. enc[slot,:]
  __shared__ __align__(16) float sPart[16*32*4];// mh partials: 16 streams x 32 quads x 4
  __shared__ __align__(16) float sq1[D];
  __shared__ __align__(16) float sq [D];
  __shared__ __align__(16) float sMh[D];
  __shared__ float sAtt[H*S0];                  // unnormalized exp(score)
  __shared__ float sSum[H];
  __shared__ float sWv[2];
  __shared__ int   sWi[2];
  __shared__ int   sSlotNode[S0];               // slot -> node id
  __shared__ int   sCur;
  __shared__ int   sSel;

  const int tid = threadIdx.x;
  const int b   = blockIdx.x;
  float wreg[D];   // per-thread weight column (registers; all index uses unrolled)

  // ---- init: visited bits, slot list, prefix -> out ----
  if (tid == 0) {
    unsigned vis0 = 0u, vis1 = 0u, vis2 = 0u, vis3 = 0u;
    const int* pr = prefix + b*KL;
    for (int j = 0; j < KL; ++j) {
      int node = pr[j];
      if (node < 32) vis0 |= 1u << node;
      else if (node < 64) vis1 |= 1u << (node-32);
      else if (node < 96) vis2 |= 1u << (node-64);
      else vis3 |= 1u << (node-96);
      out[(size_t)b*N + j] = node;
    }
    sCur = pr[KL-1];
    int cnt = 0;
    for (int n = 0; n < N; ++n) {
      unsigned w = (n < 32) ? vis0 : (n < 64) ? vis1 : (n < 96) ? vis2 : vis3;
      int bit = n & 31;
      if (!((w >> bit) & 1u)) sSlotNode[cnt++] = n;
    }
  }
  __syncthreads();

  // ---- Phase 1a: K (threads 0..255) and V (256..511), 45 slots per half ----
  {
    const int col  = tid & 127;
    const int half = (tid >> 7) & 1;
    const float* W = (tid < 256) ? Wk : Wv;
    float* dst     = (tid < 256) ? sK : sV;
    #pragma unroll
    for (int d = 0; d < D; ++d) wreg[d] = W[d*D + col];
    const int sb = half*45, se = sb + 45;
    for (int s = sb; s < se; ++s) {
      int node = __builtin_amdgcn_readfirstlane(sSlotNode[s]);
      const float* er = enc + ((size_t)b*N + node)*D;
      float acc = 0.f;
      #pragma unroll
      for (int d = 0; d < D; ++d) acc += er[d] * wreg[d];
      dst[s*LDK + col] = acc;
    }
  }
  // ---- Phase 1b: CE, all 512 threads, slot quarters ----
  {
    const int k = tid & 127;
    const int quarter = tid >> 7;
    #pragma unroll
    for (int d = 0; d < D; ++d) wreg[d] = Wcomb[k*D + d];   // row k (contiguous)
    const int sb = (S0*quarter) >> 2, se = (S0*(quarter+1)) >> 2; // 0,22,45,67,90
    for (int s = sb; s < se; ++s) {
      int node = __builtin_amdgcn_readfirstlane(sSlotNode[s]);
      const float* er = enc + ((size_t)b*N + node)*D;
      float acc = 0.f;
      #pragma unroll
      for (int d = 0; d < D; ++d) acc += er[d] * wreg[d];
      sCE[s*LDK + k] = acc;
    }
  }
  // ---- Phase 1c: q1 = enc[last0] @ Wq_first ----
  if (tid < D) {
    int last0 = __builtin_amdgcn_readfirstlane(sCur);
    const float* er = enc + ((size_t)b*N + last0)*D;
    float acc = 0.f;
    #pragma unroll
    for (int d = 0; d < D; ++d) acc += er[d] * Wq_first[d*D + tid];
    sq1[tid] = acc;
  }
  // ---- Phase 1d: persistent Wq_last column for decode ----
  if (tid < D) {
    #pragma unroll
    for (int d = 0; d < D; ++d) wreg[d] = Wq_last[d*D + tid];
  }
  __syncthreads();

  // ---- decode: 90 sequential greedy steps ----
  for (int step = 0; step < STEPS; ++step) {
    const int m = S0 - step;   // live slots

    // A: q = q1 + enc[cur] @ Wq_last   (threads 0..127)
    if (tid < D) {
      int cur = __builtin_amdgcn_readfirstlane(sCur);
      const float* er = enc + ((size_t)b*N + cur)*D;
      float acc = 0.f;
      #pragma unroll
      for (int d = 0; d < D; ++d) acc += er[d] * wreg[d];
      sq[tid] = sq1[tid] + acc;
    }
    __syncthreads();

    // B: scores + exp + per-head sum (wave w == head h; lanes = slots, x2)
    {
      const int h = tid >> 6, lane = tid & 63;
      const float* qh = &sq[h*DKH];
      const float4 q0 = *(const float4*)(qh+0);
      const float4 q1 = *(const float4*)(qh+4);
      const float4 q2 = *(const float4*)(qh+8);
      const float4 q3 = *(const float4*)(qh+12);
      float x0 = 0.f, x1 = 0.f;
      const int i0 = lane, i1 = lane + 64;
      if (i0 < m) {
        const float* kr = &sK[i0*LDK + h*DKH];
        float sdot = dot4(q0, *(const float4*)(kr+0))
                   + dot4(q1, *(const float4*)(kr+4))
                   + dot4(q2, *(const float4*)(kr+8))
                   + dot4(q3, *(const float4*)(kr+12));
        x0 = expf(sdot * 0.25f);          // score/sqrt(16); no max-sub (safe range)
        sAtt[h*S0 + i0] = x0;
      }
      if (i1 < m) {
        const float* kr = &sK[i1*LDK + h*DKH];
        float sdot = dot4(q0, *(const float4*)(kr+0))
                   + dot4(q1, *(const float4*)(kr+4))
                   + dot4(q2, *(const float4*)(kr+8))
                   + dot4(q3, *(const float4*)(kr+12));
        x1 = expf(sdot * 0.25f);
        sAtt[h*S0 + i1] = x1;
      }
      float loc = x0 + x1;
      #pragma unroll
      for (int off = 32; off; off >>= 1) loc += __shfl_xor(loc, off);
      if (lane == 0) sSum[h] = loc;
    }
    __syncthreads();

    // C: mh partials.  thread -> (e-quad, slot-stream); 16 slot streams
    {
      const int quad = tid & 31;           // e = quad*4 .. quad*4+3
      const int strm = tid >> 5;           // 0..15
      const int h = quad >> 2;
      float4 acc = make_float4(0.f, 0.f, 0.f, 0.f);
      for (int i = strm; i < m; i += 16) {
        const float a = sAtt[h*S0 + i];
        const float4 v = *(const float4*)&sV[i*LDK + quad*4];
        acc.x += a*v.x; acc.y += a*v.y; acc.z += a*v.z; acc.w += a*v.w;
      }
      *(float4*)&sPart[(strm*32 + quad)*4] = acc;
    }
    __syncthreads();

    // C2: combine partials + normalize by softmax sum
    if (tid < D) {
      const int h = tid >> 4;
      float v = 0.f;
      #pragma unroll
      for (int p = 0; p < 16; ++p) v += sPart[p*128 + tid];
      sMh[tid] = v / sSum[h];
    }
    __syncthreads();

    // D: sc = mh . CE[slot] / sqrt(128); logits = 10*tanh(sc); wave argmax
    if (tid < 2*64) {
      const int w = tid >> 6, lane = tid & 63;
      const int i = tid;                   // slot
      float val = -INFINITY;
      if (i < m) {
        float acc = 0.f;
        #pragma unroll
        for (int c = 0; c < 32; ++c) {
          const float4 mh4 = *(const float4*)&sMh[c*4];
          const float4 ce  = *(const float4*)&sCE[i*LDK + c*4];
          acc += dot4(mh4, ce);
        }
        const float sc = acc / sqrtf((float)D);
        val = 10.0f * tanhf(sc);
      }
      int idx = i;
      #pragma unroll
      for (int off = 32; off; off >>= 1) {
        float ov = __shfl_xor(val, off);
        int   oi = __shfl_xor(idx, off);
        if (ov > val || (ov == val && oi < idx)) { val = ov; idx = oi; }
      }
      if (lane == 0) { sWv[w] = val; sWi[w] = idx; }
    }
    __syncthreads();

    if (tid == 0) {
      const int isel = (sWv[1] > sWv[0]) ? sWi[1] : sWi[0];
      const int node = sSlotNode[isel];
      out[(size_t)b*N + KL + step] = node;
      sCur = node;
      sSel = isel;
    }
    __syncthreads();

    // E: swap-remove selected slot (copy last live row over it)
    {
      const int last = m - 1;
      const int isel = sSel;
      if (tid < LDK)            sK [isel*LDK + tid]         = sK [last*LDK + tid];
      else if (tid < 2*LDK)     sV [isel*LDK + (tid-LDK)]   = sV [last*LDK + (tid-LDK)];
      else if (tid < 3*LDK)     sCE[isel*LDK + (tid-2*LDK)] = sCE[last*LDK + (tid-2*LDK)];
      else if (tid == 3*LDK)    sSlotNode[isel] = sSlotNode[last];
    }
    __syncthreads();
  }
}

extern "C" void kernel_launch(void* const* d_in, const int* in_sizes, int n_in,
                              void* d_out, int out_size, void* d_ws, size_t ws_size,
                              hipStream_t stream) {
  // inputs: 0 problems (unused), 1 encoded_nodes f32, 2 Wq_first, 3 Wq_last,
  //         4 Wk, 5 Wv, 6 Wcomb, 7 prefix i32
  const float* enc      = (const float*)d_in[1];
  const float* Wq_first = (const float*)d_in[2];
  const float* Wq_last  = (const float*)d_in[3];
  const float* Wk       = (const float*)d_in[4];
  const float* Wv       = (const float*)d_in[5];
  const float* Wcomb    = (const float*)d_in[6];
  const int*   prefix   = (const int*)d_in[7];
  const int batch = in_sizes[7] / KL;   // 2048
  policy_kernel<<<batch, NT, 0, stream>>>(enc, Wq_first, Wq_last, Wk, Wv, Wcomb,
                                          prefix, (int*)d_out);
}

// Round 3
// 3427.257 us; speedup vs baseline: 1.2740x; 1.2740x over previous
//
#include <hip/hip_runtime.h>
#include <math.h>

#define N      100   // nodes per problem
#define D      128   // embedding dim = H*DKH
#define H      8
#define DKH    16
#define KL     10    // prefix length
#define S0     90    // unvisited slots (fixed, no compaction)
#define STEPS  90
#define LDK    132   // padded LDS row stride (floats) for sK/sCE
#define NT     512

__device__ __forceinline__ float dot4(float4 a, float4 b) {
  return a.x*b.x + a.y*b.y + a.z*b.z + a.w*b.w;
}
__device__ __forceinline__ void fma4(float4& acc, float a, float4 v) {
  acc.x += a*v.x; acc.y += a*v.y; acc.z += a*v.z; acc.w += a*v.w;
}

__global__ __launch_bounds__(NT, 2)
void policy_kernel(const float* __restrict__ enc,
                   const float* __restrict__ Wq_first,
                   const float* __restrict__ Wq_last,
                   const float* __restrict__ Wk,
                   const float* __restrict__ Wv,
                   const float* __restrict__ Wcomb,
                   const int*   __restrict__ prefix,
                   int*         __restrict__ out) {
  // ---- LDS ≈ 154.7 KB ----
  __shared__ __align__(16) float sK [S0*LDK];      // K[slot][j]      47.5 KB
  __shared__ __align__(16) float sCE[S0*LDK];      // CE[slot][k]     47.5 KB (also V staging)
  __shared__ __align__(16) float sQL[(S0+1)*D];    // qP[row][j]=q1+qlast  46.6 KB
  __shared__ __align__(16) float sPart[16*32*4];   // mh partials      8 KB
  __shared__ __align__(16) float sq1[D];
  __shared__ __align__(16) float sMh[D];
  __shared__ float sAtt[H*S0];                     // unnormalized exp(score)
  __shared__ float sSum[H];                        // per-head softmax partition sum
  __shared__ float sVisF[96];                      // 0 or -inf per slot
  __shared__ int   sSlotNode[96];                  // slot -> node id (ascending, fixed)
  __shared__ float sWv[8];
  __shared__ int   sWi[8];
  __shared__ int   sCurRow;                        // row in sQL of current node
  __shared__ int   sLast0;

  const int tid = threadIdx.x;
  const int b   = blockIdx.x;
  const size_t encBase = (size_t)b * N * D;

  // ---- init ----
  if (tid < 96) sVisF[tid] = 0.f;
  if (tid < KL) out[(size_t)b*N + tid] = prefix[b*KL + tid];
  if (tid == 0) {
    unsigned vis[4] = {0u,0u,0u,0u};
    const int* pr = prefix + b*KL;
    for (int j = 0; j < KL; ++j) { int n = pr[j]; vis[n>>5] |= 1u << (n&31); }
    int cnt = 0;
    for (int n = 0; n < N; ++n)
      if (!((vis[n>>5] >> (n&31)) & 1u)) sSlotNode[cnt++] = n;
    sCurRow = S0;              // row S0 holds qP for last0
    sLast0  = pr[KL-1];
  }
  __syncthreads();

  const int col = tid & 127;
  const int grp = tid >> 7;    // 0..3; waves are grp-uniform (tid 0..127 = grp 0, ...)

  // cache node ids for this grp's rows (wave-uniform)
  int nd[23];
  #pragma unroll
  for (int ii = 0; ii < 23; ++ii) {
    int i = grp + 4*ii;
    nd[ii] = (i < S0) ? __builtin_amdgcn_readfirstlane(sSlotNode[i]) : 0;
  }

  // ---- phase 1: K -> sK, V -> sCE (staging), q1 -> sq1 ----
  {
    float acc[23];
    #pragma unroll
    for (int ii = 0; ii < 23; ++ii) acc[ii] = 0.f;
    for (int dd = 0; dd < D; dd += 16) {
      float w[16];
      #pragma unroll
      for (int t = 0; t < 16; ++t) w[t] = Wk[(dd+t)*D + col];
      #pragma unroll
      for (int ii = 0; ii < 23; ++ii) {
        if (grp + 4*ii < S0) {
          const float* er = enc + encBase + (size_t)nd[ii]*D + dd;
          float a0=0,a1=0,a2=0,a3=0;
          #pragma unroll
          for (int t = 0; t < 16; t += 4) {
            a0 += er[t]*w[t]; a1 += er[t+1]*w[t+1];
            a2 += er[t+2]*w[t+2]; a3 += er[t+3]*w[t+3];
          }
          acc[ii] += (a0+a1)+(a2+a3);
        }
      }
    }
    #pragma unroll
    for (int ii = 0; ii < 23; ++ii) { int i = grp+4*ii; if (i < S0) sK[i*LDK + col] = acc[ii]; }
  }
  {
    float acc[23];
    #pragma unroll
    for (int ii = 0; ii < 23; ++ii) acc[ii] = 0.f;
    for (int dd = 0; dd < D; dd += 16) {
      float w[16];
      #pragma unroll
      for (int t = 0; t < 16; ++t) w[t] = Wv[(dd+t)*D + col];
      #pragma unroll
      for (int ii = 0; ii < 23; ++ii) {
        if (grp + 4*ii < S0) {
          const float* er = enc + encBase + (size_t)nd[ii]*D + dd;
          float a0=0,a1=0,a2=0,a3=0;
          #pragma unroll
          for (int t = 0; t < 16; t += 4) {
            a0 += er[t]*w[t]; a1 += er[t+1]*w[t+1];
            a2 += er[t+2]*w[t+2]; a3 += er[t+3]*w[t+3];
          }
          acc[ii] += (a0+a1)+(a2+a3);
        }
      }
    }
    #pragma unroll
    for (int ii = 0; ii < 23; ++ii) { int i = grp+4*ii; if (i < S0) sCE[i*LDK + col] = acc[ii]; }
  }
  if (tid < D) {  // q1 = enc[last0] @ Wq_first
    const int last0 = sLast0;
    const float* er = enc + encBase + (size_t)last0*D;
    float a0=0,a1=0,a2=0,a3=0;
    #pragma unroll
    for (int d = 0; d < D; d += 4) {
      a0 += er[d]  *Wq_first[d*D     + tid];
      a1 += er[d+1]*Wq_first[(d+1)*D + tid];
      a2 += er[d+2]*Wq_first[(d+2)*D + tid];
      a3 += er[d+3]*Wq_first[(d+3)*D + tid];
    }
    sq1[tid] = (a0+a1)+(a2+a3);
  }
  __syncthreads();

  // ---- phase 2a: V fragments LDS -> registers (fixed slot layout) ----
  const int strm = tid >> 5;   // 0..15
  const int quad = tid & 31;   // 0..31
  float4 v0, v1, v2, v3, v4, v5;
  v0 = *(const float4*)&sCE[(strm     )*LDK + quad*4];
  v1 = *(const float4*)&sCE[(strm + 16)*LDK + quad*4];
  v2 = *(const float4*)&sCE[(strm + 32)*LDK + quad*4];
  v3 = *(const float4*)&sCE[(strm + 48)*LDK + quad*4];
  v4 = *(const float4*)&sCE[(strm + 64)*LDK + quad*4];
  v5 = (strm < 10) ? *(const float4*)&sCE[(strm + 80)*LDK + quad*4]
                   : make_float4(0.f,0.f,0.f,0.f);
  __syncthreads();

  // ---- phase 2b: CE -> sCE (overwrite), qP -> sQL ----
  {
    float acc[23];
    #pragma unroll
    for (int ii = 0; ii < 23; ++ii) acc[ii] = 0.f;
    for (int dd = 0; dd < D; dd += 16) {
      float w[16];
      #pragma unroll
      for (int t = 0; t < 16; ++t) w[t] = Wcomb[col*D + dd + t];   // row k=col, contiguous
      #pragma unroll
      for (int ii = 0; ii < 23; ++ii) {
        if (grp + 4*ii < S0) {
          const float* er = enc + encBase + (size_t)nd[ii]*D + dd;
          float a0=0,a1=0,a2=0,a3=0;
          #pragma unroll
          for (int t = 0; t < 16; t += 4) {
            a0 += er[t]*w[t]; a1 += er[t+1]*w[t+1];
            a2 += er[t+2]*w[t+2]; a3 += er[t+3]*w[t+3];
          }
          acc[ii] += (a0+a1)+(a2+a3);
        }
      }
    }
    #pragma unroll
    for (int ii = 0; ii < 23; ++ii) { int i = grp+4*ii; if (i < S0) sCE[i*LDK + col] = acc[ii]; }
  }
  {
    int ndq[23];
    #pragma unroll
    for (int ii = 0; ii < 23; ++ii) {
      int i = grp + 4*ii;
      ndq[ii] = (i < S0) ? nd[ii] : ((i == S0) ? sLast0 : 0);
    }
    float acc[23];
    #pragma unroll
    for (int ii = 0; ii < 23; ++ii) acc[ii] = 0.f;
    for (int dd = 0; dd < D; dd += 16) {
      float w[16];
      #pragma unroll
      for (int t = 0; t < 16; ++t) w[t] = Wq_last[(dd+t)*D + col];
      #pragma unroll
      for (int ii = 0; ii < 23; ++ii) {
        if (grp + 4*ii <= S0) {
          const float* er = enc + encBase + (size_t)ndq[ii]*D + dd;
          float a0=0,a1=0,a2=0,a3=0;
          #pragma unroll
          for (int t = 0; t < 16; t += 4) {
            a0 += er[t]*w[t]; a1 += er[t+1]*w[t+1];
            a2 += er[t+2]*w[t+2]; a3 += er[t+3]*w[t+3];
          }
          acc[ii] += (a0+a1)+(a2+a3);
        }
      }
    }
    const float q1c = sq1[col];
    #pragma unroll
    for (int ii = 0; ii < 23; ++ii) { int i = grp+4*ii; if (i <= S0) sQL[i*D + col] = acc[ii] + q1c; }
  }
  __syncthreads();

  // ---- decode: 90 sequential greedy steps, 5 barriers/step ----
  const int h    = tid >> 6;     // wave = head
  const int lane = tid & 63;
  const int di   = tid >> 2;     // phase D: slot
  const int dkc  = tid & 3;      // phase D: k-chunk

  for (int step = 0; step < STEPS; ++step) {
    // B: att[i] = exp(score/4 + vis[i]); per-head partition sum via shuffle
    {
      const int curRow = sCurRow;
      const float* qr = &sQL[curRow*D + h*DKH];
      const float4 q0 = *(const float4*)(qr+0);
      const float4 q1 = *(const float4*)(qr+4);
      const float4 q2 = *(const float4*)(qr+8);
      const float4 q3 = *(const float4*)(qr+12);
      float x0, x1 = 0.f;
      {
        const int i0 = lane;                       // < 90 always
        const float* kr = &sK[i0*LDK + h*DKH];
        float s = dot4(q0, *(const float4*)(kr+0))
                + dot4(q1, *(const float4*)(kr+4))
                + dot4(q2, *(const float4*)(kr+8))
                + dot4(q3, *(const float4*)(kr+12));
        x0 = expf(s*0.25f + sVisF[i0]);
        sAtt[h*S0 + i0] = x0;
      }
      if (lane < S0 - 64) {                        // 26 lanes
        const int i1 = 64 + lane;
        const float* kr = &sK[i1*LDK + h*DKH];
        float s = dot4(q0, *(const float4*)(kr+0))
                + dot4(q1, *(const float4*)(kr+4))
                + dot4(q2, *(const float4*)(kr+8))
                + dot4(q3, *(const float4*)(kr+12));
        x1 = expf(s*0.25f + sVisF[i1]);
        sAtt[h*S0 + i1] = x1;
      }
      float loc = x0 + x1;                         // per-head partition sum
      #pragma unroll
      for (int off = 32; off; off >>= 1) loc += __shfl_xor(loc, off);
      if (lane == 0) sSum[h] = loc;
    }
    __syncthreads();

    // C: mh partials from register-resident V
    {
      const int ch = quad >> 2;
      float4 acc = make_float4(0.f,0.f,0.f,0.f);
      fma4(acc, sAtt[ch*S0 + strm     ], v0);
      fma4(acc, sAtt[ch*S0 + strm + 16], v1);
      fma4(acc, sAtt[ch*S0 + strm + 32], v2);
      fma4(acc, sAtt[ch*S0 + strm + 48], v3);
      fma4(acc, sAtt[ch*S0 + strm + 64], v4);
      if (strm < 10) fma4(acc, sAtt[ch*S0 + strm + 80], v5);
      *(float4*)&sPart[(strm*32 + quad)*4] = acc;
    }
    __syncthreads();

    // C2: reduce 16 partial streams; normalize PER HEAD (argmax depends on it!)
    if (tid < D) {
      float s = 0.f;
      #pragma unroll
      for (int p = 0; p < 16; ++p) s += sPart[p*128 + tid];
      sMh[tid] = s / sSum[tid >> 4];
    }
    __syncthreads();

    // D: sc[i] = mh . CE[i]  (scale + tanh dropped: strictly monotone)
    if (tid < 384) {
      float acc0 = 0.f, acc1 = 0.f;
      if (di < S0) {
        #pragma unroll
        for (int j = 0; j < 8; j += 2) {
          const float4 ce0 = *(const float4*)&sCE[di*LDK + dkc*32 + j*4];
          const float4 mh0 = *(const float4*)&sMh[dkc*32 + j*4];
          const float4 ce1 = *(const float4*)&sCE[di*LDK + dkc*32 + (j+1)*4];
          const float4 mh1 = *(const float4*)&sMh[dkc*32 + (j+1)*4];
          acc0 += dot4(mh0, ce0);
          acc1 += dot4(mh1, ce1);
        }
      }
      float acc = acc0 + acc1;
      acc += __shfl_xor(acc, 1);
      acc += __shfl_xor(acc, 2);
      float val = (di < S0) ? acc + sVisF[di] : -INFINITY;
      int   idx = (di < S0) ? di : 127;
      #pragma unroll
      for (int off = 32; off; off >>= 1) {
        float ov = __shfl_xor(val, off);
        int   oi = __shfl_xor(idx, off);
        if (ov > val || (ov == val && oi < idx)) { val = ov; idx = oi; }
      }
      if (lane == 0) { sWv[h] = val; sWi[h] = idx; }
    }
    __syncthreads();

    // E: pick winner across 6 waves; update state
    if (tid == 0) {
      float bv = sWv[0]; int bi = sWi[0];
      #pragma unroll
      for (int w = 1; w < 6; ++w) { float v = sWv[w]; if (v > bv) { bv = v; bi = sWi[w]; } }
      out[(size_t)b*N + KL + step] = sSlotNode[bi];
      sCurRow = bi;
      sVisF[bi] = -INFINITY;
    }
    __syncthreads();
  }
}

extern "C" void kernel_launch(void* const* d_in, const int* in_sizes, int n_in,
                              void* d_out, int out_size, void* d_ws, size_t ws_size,
                              hipStream_t stream) {
  // inputs: 0 problems (unused), 1 encoded_nodes f32, 2 Wq_first, 3 Wq_last,
  //         4 Wk, 5 Wv, 6 Wcomb, 7 prefix i32
  const float* enc      = (const float*)d_in[1];
  const float* Wq_first = (const float*)d_in[2];
  const float* Wq_last  = (const float*)d_in[3];
  const float* Wk       = (const float*)d_in[4];
  const float* Wv       = (const float*)d_in[5];
  const float* Wcomb    = (const float*)d_in[6];
  const int*   prefix   = (const int*)d_in[7];
  const int batch = in_sizes[7] / KL;   // 2048
  policy_kernel<<<batch, NT, 0, stream>>>(enc, Wq_first, Wq_last, Wk, Wv, Wcomb,
                                          prefix, (int*)d_out);
}

// Round 4
// 2557.142 us; speedup vs baseline: 1.7075x; 1.3403x over previous
//
#include <hip/hip_runtime.h>
#include <math.h>

#define N      100   // nodes per problem
#define D      128   // embedding dim = H*DKH
#define H      8
#define DKH    16
#define KL     10    // prefix length
#define S0     90    // unvisited slots (fixed)
#define STEPS  90
#define SROWS  48    // staging chunk rows (chunk A=48, B=42)
#define LDK    132   // staging stride (floats): 33 float4s (odd) -> conflict-friendly
#define NT     512

__device__ __forceinline__ float dot4(float4 a, float4 b) {
  return a.x*b.x + a.y*b.y + a.z*b.z + a.w*b.w;
}
__device__ __forceinline__ void fma4(float4& acc, float a, float4 v) {
  acc.x += a*v.x; acc.y += a*v.y; acc.z += a*v.z; acc.w += a*v.w;
}

// Compute rows [base, base+cnt) of E@W (or Wcomb row-major) into stage[row*LDK+col].
__device__ __forceinline__ void compute_chunk(const float* __restrict__ encB,
                                              const float* __restrict__ W,
                                              bool wRowMajor, int base, int cnt,
                                              const int* __restrict__ slotNode,
                                              float* __restrict__ stage, int tid) {
  const int col = tid & 127;
  const int grp = tid >> 7;
  float acc[12];
  int   nd [12];
  #pragma unroll
  for (int ii = 0; ii < 12; ++ii) {
    acc[ii] = 0.f;
    int r = grp + 4*ii;
    nd[ii] = (r < cnt) ? __builtin_amdgcn_readfirstlane(slotNode[base + r]) : 0;
  }
  for (int dd = 0; dd < D; dd += 16) {
    float w[16];
    #pragma unroll
    for (int t = 0; t < 16; ++t)
      w[t] = wRowMajor ? W[col*D + dd + t] : W[(dd+t)*D + col];
    #pragma unroll
    for (int ii = 0; ii < 12; ++ii) {
      int r = grp + 4*ii;
      if (r < cnt) {
        const float* er = encB + (size_t)nd[ii]*D + dd;
        float a0=0,a1=0,a2=0,a3=0;
        #pragma unroll
        for (int t = 0; t < 16; t += 4) {
          a0 += er[t]*w[t];   a1 += er[t+1]*w[t+1];
          a2 += er[t+2]*w[t+2]; a3 += er[t+3]*w[t+3];
        }
        acc[ii] += (a0+a1)+(a2+a3);
      }
    }
  }
  #pragma unroll
  for (int ii = 0; ii < 12; ++ii) {
    int r = grp + 4*ii;
    if (r < cnt) stage[r*LDK + col] = acc[ii];
  }
}

__global__ __launch_bounds__(NT, 4)   // 4 waves/EU -> <=128 VGPR -> 2 blocks/CU
void policy_kernel(const float* __restrict__ enc,
                   const float* __restrict__ Wq_first,
                   const float* __restrict__ Wq_last,
                   const float* __restrict__ Wk,
                   const float* __restrict__ Wv,
                   const float* __restrict__ Wcomb,
                   const int*   __restrict__ prefix,
                   int*         __restrict__ out) {
  // ---- LDS ~76 KB -> 2 blocks/CU ----
  __shared__ __align__(16) float sQL[(S0+1)*D];     // 46.6 KB qP table
  __shared__ __align__(16) float sStage[SROWS*LDK]; // 25.3 KB staging / scratch
  __shared__ __align__(16) float sAtt[H*96];        // 3 KB (pad 96: bank-clean)
  __shared__ __align__(16) float sMh[D];            // 512 B (also q1 scratch)
  __shared__ float sSum[H];
  __shared__ int   sSlotNode[96];
  __shared__ unsigned long long sPacked;
  __shared__ int   sLast0;

  const int tid = threadIdx.x;
  const int b   = blockIdx.x;
  const float* encB = enc + (size_t)b*N*D;

  // ---- init ----
  if (tid < KL) out[(size_t)b*N + tid] = prefix[b*KL + tid];
  if (tid < 48) sAtt[(tid/6)*96 + 90 + (tid%6)] = 0.f;   // pad entries read by C
  if (tid == 0) {
    unsigned vis[4] = {0u,0u,0u,0u};
    const int* pr = prefix + b*KL;
    for (int j = 0; j < KL; ++j) { int n = pr[j]; vis[n>>5] |= 1u << (n&31); }
    int cnt = 0;
    for (int n = 0; n < N; ++n)
      if (!((vis[n>>5] >> (n&31)) & 1u)) sSlotNode[cnt++] = n;
    sLast0  = pr[KL-1];
    sPacked = 0ull;
  }
  __syncthreads();

  // ---- q1 = enc[last0] @ Wq_first  -> sMh (scratch) ----
  if (tid < D) {
    const int last0 = sLast0;
    const float* er = encB + (size_t)last0*D;
    float a0=0,a1=0,a2=0,a3=0;
    #pragma unroll
    for (int d = 0; d < D; d += 4) {
      a0 += er[d]  *Wq_first[d*D     + tid];
      a1 += er[d+1]*Wq_first[(d+1)*D + tid];
      a2 += er[d+2]*Wq_first[(d+2)*D + tid];
      a3 += er[d+3]*Wq_first[(d+3)*D + tid];
    }
    sMh[tid] = (a0+a1)+(a2+a3);
  }
  __syncthreads();

  // ---- qP[r] = q1 + enc[row_r] @ Wq_last -> sQL (rows 0..90) ----
  {
    const int col = tid & 127;
    const int grp = tid >> 7;
    float acc[23];
    int   nd [23];
    #pragma unroll
    for (int ii = 0; ii < 23; ++ii) {
      acc[ii] = 0.f;
      int r = grp + 4*ii;
      nd[ii] = (r < S0) ? __builtin_amdgcn_readfirstlane(sSlotNode[r])
                        : ((r == S0) ? sLast0 : 0);
    }
    for (int dd = 0; dd < D; dd += 16) {
      float w[16];
      #pragma unroll
      for (int t = 0; t < 16; ++t) w[t] = Wq_last[(dd+t)*D + col];
      #pragma unroll
      for (int ii = 0; ii < 23; ++ii) {
        int r = grp + 4*ii;
        if (r <= S0) {
          const float* er = encB + (size_t)nd[ii]*D + dd;
          float a0=0,a1=0,a2=0,a3=0;
          #pragma unroll
          for (int t = 0; t < 16; t += 4) {
            a0 += er[t]*w[t];   a1 += er[t+1]*w[t+1];
            a2 += er[t+2]*w[t+2]; a3 += er[t+3]*w[t+3];
          }
          acc[ii] += (a0+a1)+(a2+a3);
        }
      }
    }
    const float q1c = sMh[col];
    #pragma unroll
    for (int ii = 0; ii < 23; ++ii) {
      int r = grp + 4*ii;
      if (r <= S0) sQL[r*D + col] = acc[ii] + q1c;
    }
  }
  __syncthreads();

  // role indices
  const int h     = tid >> 6;   // phase B: wave = head
  const int l     = tid & 63;   // lane
  const int cQuad = tid >> 4;   // phase C: output quad (0..31)
  const int cStrm = tid & 15;   // phase C: slot stream (0..15)
  const int di    = tid >> 2;   // phase D: slot row (0..127)
  const int dkc   = tid & 3;    // phase D: k-chunk

  // ---- K fragments: wave h, lane l holds rows l and l+64, slice [16h..16h+16) ----
  float4 ka0,ka1,ka2,ka3, kb0,kb1,kb2,kb3;
  compute_chunk(encB, Wk, false, 0, 48, sSlotNode, sStage, tid);
  __syncthreads();
  if (l < 48) {
    const float* p = &sStage[l*LDK + h*DKH];
    ka0 = *(const float4*)(p+0);  ka1 = *(const float4*)(p+4);
    ka2 = *(const float4*)(p+8);  ka3 = *(const float4*)(p+12);
  }
  __syncthreads();
  compute_chunk(encB, Wk, false, 48, 42, sSlotNode, sStage, tid);
  __syncthreads();
  if (l >= 48) {
    const float* p = &sStage[(l-48)*LDK + h*DKH];
    ka0 = *(const float4*)(p+0);  ka1 = *(const float4*)(p+4);
    ka2 = *(const float4*)(p+8);  ka3 = *(const float4*)(p+12);
  }
  if (l < 26) {
    const float* p = &sStage[(l+16)*LDK + h*DKH];   // row 64+l -> stage row l+16
    kb0 = *(const float4*)(p+0);  kb1 = *(const float4*)(p+4);
    kb2 = *(const float4*)(p+8);  kb3 = *(const float4*)(p+12);
  } else {
    kb0=kb1=kb2=kb3 = make_float4(0.f,0.f,0.f,0.f);
  }
  __syncthreads();

  // ---- V fragments: thread (cQuad,cStrm) holds V[cStrm+16t][cQuad*4..+3] ----
  float4 v0,v1,v2,v3,v4,v5;
  compute_chunk(encB, Wv, false, 0, 48, sSlotNode, sStage, tid);
  __syncthreads();
  v0 = *(const float4*)&sStage[(cStrm     )*LDK + cQuad*4];
  v1 = *(const float4*)&sStage[(cStrm + 16)*LDK + cQuad*4];
  v2 = *(const float4*)&sStage[(cStrm + 32)*LDK + cQuad*4];
  __syncthreads();
  compute_chunk(encB, Wv, false, 48, 42, sSlotNode, sStage, tid);
  __syncthreads();
  v3 = *(const float4*)&sStage[(cStrm     )*LDK + cQuad*4];   // row 48+cStrm
  v4 = *(const float4*)&sStage[(cStrm + 16)*LDK + cQuad*4];   // row 64+cStrm
  v5 = (cStrm < 10) ? *(const float4*)&sStage[(cStrm + 32)*LDK + cQuad*4]  // row 80+cStrm
                    : make_float4(0.f,0.f,0.f,0.f);
  __syncthreads();

  // ---- CE fragments: thread (di,dkc) holds CE[di][dkc*32 + j*4 ..] ----
  float4 ce[8];
  compute_chunk(encB, Wcomb, true, 0, 48, sSlotNode, sStage, tid);
  __syncthreads();
  if (di < 48) {
    #pragma unroll
    for (int j = 0; j < 8; ++j)
      ce[j] = *(const float4*)&sStage[di*LDK + dkc*32 + j*4];
  }
  __syncthreads();
  compute_chunk(encB, Wcomb, true, 48, 42, sSlotNode, sStage, tid);
  __syncthreads();
  if (di >= 48 && di < S0) {
    #pragma unroll
    for (int j = 0; j < 8; ++j)
      ce[j] = *(const float4*)&sStage[(di-48)*LDK + dkc*32 + j*4];
  }
  __syncthreads();

  // ---- decode: 90 steps, 3 barriers/step, visited state in registers ----
  float visA = 0.f, visB = 0.f, visD = 0.f;
  int   curRow = S0;

  for (int step = 0; step < STEPS; ++step) {
    if (step > 0) {
      const unsigned long long u = sPacked;          // winner of previous step
      const int idx = 127 - (int)(u & 0xFFull);
      if (tid == 0) out[(size_t)b*N + KL + step - 1] = sSlotNode[idx];
      curRow = idx;
      if (idx == l)      visA = -INFINITY;
      if (idx == l + 64) visB = -INFINITY;
      if (idx == di)     visD = -INFINITY;
    }

    // B: att + per-head partition sum
    {
      const float* qr = &sQL[curRow*D + h*DKH];      // wave-uniform -> broadcast
      const float4 q0 = *(const float4*)(qr+0);
      const float4 q1 = *(const float4*)(qr+4);
      const float4 q2 = *(const float4*)(qr+8);
      const float4 q3 = *(const float4*)(qr+12);
      float s0 = dot4(q0,ka0)+dot4(q1,ka1)+dot4(q2,ka2)+dot4(q3,ka3);
      float x0 = expf(s0*0.25f + visA);
      sAtt[h*96 + l] = x0;
      float x1 = 0.f;
      if (l < 26) {
        float s1 = dot4(q0,kb0)+dot4(q1,kb1)+dot4(q2,kb2)+dot4(q3,kb3);
        x1 = expf(s1*0.25f + visB);
        sAtt[h*96 + 64 + l] = x1;
      }
      float loc = x0 + x1;
      #pragma unroll
      for (int off = 32; off; off >>= 1) loc += __shfl_xor(loc, off);
      if (l == 0) sSum[h] = loc;
    }
    __syncthreads();

    // C: mh (fused reduce via 16-lane butterfly) + reset sPacked
    {
      if (tid == 0) sPacked = 0ull;
      const int ch = cQuad >> 2;
      float4 acc = make_float4(0.f,0.f,0.f,0.f);
      fma4(acc, sAtt[ch*96 + cStrm     ], v0);
      fma4(acc, sAtt[ch*96 + cStrm + 16], v1);
      fma4(acc, sAtt[ch*96 + cStrm + 32], v2);
      fma4(acc, sAtt[ch*96 + cStrm + 48], v3);
      fma4(acc, sAtt[ch*96 + cStrm + 64], v4);
      fma4(acc, sAtt[ch*96 + cStrm + 80], v5);       // v5=0 for cStrm>=10; pad att=0
      #pragma unroll
      for (int off = 1; off < 16; off <<= 1) {
        acc.x += __shfl_xor(acc.x, off);
        acc.y += __shfl_xor(acc.y, off);
        acc.z += __shfl_xor(acc.z, off);
        acc.w += __shfl_xor(acc.w, off);
      }
      if (cStrm == 0) {
        const float r = 1.0f / sSum[ch];
        float4 o; o.x = acc.x*r; o.y = acc.y*r; o.z = acc.z*r; o.w = acc.w*r;
        *(float4*)&sMh[cQuad*4] = o;
      }
    }
    __syncthreads();

    // D: sc + argmax -> packed atomicMax
    if (tid < 384) {
      float a = 0.f;
      #pragma unroll
      for (int j = 0; j < 8; ++j) {
        const float4 mh = *(const float4*)&sMh[dkc*32 + j*4];
        a += dot4(ce[j], mh);
      }
      a += __shfl_xor(a, 1);
      a += __shfl_xor(a, 2);
      float val = (di < S0) ? a + visD : -INFINITY;
      int   idx = (di < S0) ? di : 127;
      #pragma unroll
      for (int off = 32; off; off >>= 1) {
        float ov = __shfl_xor(val, off);
        int   oi = __shfl_xor(idx, off);
        if (ov > val || (ov == val && oi < idx)) { val = ov; idx = oi; }
      }
      if (l == 0) {
        unsigned s = __float_as_uint(val);
        s = (s & 0x80000000u) ? ~s : (s | 0x80000000u);
        unsigned long long pk = ((unsigned long long)s << 32)
                              | (unsigned long long)(unsigned)(127 - idx);
        atomicMax(&sPacked, pk);
      }
    }
    __syncthreads();
  }

  if (tid == 0) {   // final winner
    const unsigned long long u = sPacked;
    const int idx = 127 - (int)(u & 0xFFull);
    out[(size_t)b*N + KL + STEPS - 1] = sSlotNode[idx];
  }
}

extern "C" void kernel_launch(void* const* d_in, const int* in_sizes, int n_in,
                              void* d_out, int out_size, void* d_ws, size_t ws_size,
                              hipStream_t stream) {
  // inputs: 0 problems (unused), 1 encoded_nodes f32, 2 Wq_first, 3 Wq_last,
  //         4 Wk, 5 Wv, 6 Wcomb, 7 prefix i32
  const float* enc      = (const float*)d_in[1];
  const float* Wq_first = (const float*)d_in[2];
  const float* Wq_last  = (const float*)d_in[3];
  const float* Wk       = (const float*)d_in[4];
  const float* Wv       = (const float*)d_in[5];
  const float* Wcomb    = (const float*)d_in[6];
  const int*   prefix   = (const int*)d_in[7];
  const int batch = in_sizes[7] / KL;   // 2048
  policy_kernel<<<batch, NT, 0, stream>>>(enc, Wq_first, Wq_last, Wk, Wv, Wcomb,
                                          prefix, (int*)d_out);
}

// Round 5
// 2546.453 us; speedup vs baseline: 1.7147x; 1.0042x over previous
//
#include <hip/hip_runtime.h>
#include <math.h>

#define N      100   // nodes per problem
#define D      128   // embedding dim = H*DKH
#define KL     10    // prefix length
#define S0     90    // unvisited slots (fixed)
#define STEPS  90
#define LDK    132   // LDS row stride (floats); odd float4 count
#define NT     512

__device__ __forceinline__ float dot4(float4 a, float4 b) {
  return a.x*b.x + a.y*b.y + a.z*b.z + a.w*b.w;
}
__device__ __forceinline__ void fma4(float4& acc, float a, float4 v) {
  acc.x += a*v.x; acc.y += a*v.y; acc.z += a*v.z; acc.w += a*v.w;
}

// Rows [base, base+cnt) of E@W (col-major W) or Wcomb (row-major) -> stage[row*LDK+col].
// RPT bounds the per-call register working set (acc[RPT]+nd[RPT]+w[16]).
template<int RPT>
__device__ __forceinline__ void cc(const float* __restrict__ encB,
                                   const float* __restrict__ W,
                                   bool wRowMajor, int base, int cnt,
                                   const int* __restrict__ slotNode,
                                   float* __restrict__ stage, int tid) {
  const int col = tid & 127;
  const int grp = tid >> 7;
  float acc[RPT];
  int   nd [RPT];
  #pragma unroll
  for (int ii = 0; ii < RPT; ++ii) {
    acc[ii] = 0.f;
    int r = grp + 4*ii;
    nd[ii] = (r < cnt) ? __builtin_amdgcn_readfirstlane(slotNode[base + r]) : 0;
  }
  for (int dd = 0; dd < D; dd += 16) {
    float w[16];
    #pragma unroll
    for (int t = 0; t < 16; ++t)
      w[t] = wRowMajor ? W[col*D + dd + t] : W[(dd+t)*D + col];
    #pragma unroll
    for (int ii = 0; ii < RPT; ++ii) {
      int r = grp + 4*ii;
      if (r < cnt) {
        const float* er = encB + (size_t)nd[ii]*D + dd;
        float a0=0,a1=0,a2=0,a3=0;
        #pragma unroll
        for (int t = 0; t < 16; t += 4) {
          a0 += er[t]*w[t];   a1 += er[t+1]*w[t+1];
          a2 += er[t+2]*w[t+2]; a3 += er[t+3]*w[t+3];
        }
        acc[ii] += (a0+a1)+(a2+a3);
      }
    }
  }
  #pragma unroll
  for (int ii = 0; ii < RPT; ++ii) {
    int r = grp + 4*ii;
    if (r < cnt) stage[(base + r)*LDK + col] = acc[ii];
  }
}

__global__ __launch_bounds__(NT, 4)   // 4 waves/EU -> <=128 VGPR -> 2 blocks/CU
void policy_kernel(const float* __restrict__ enc,
                   const float* __restrict__ Wq_first,
                   const float* __restrict__ Wq_last,
                   const float* __restrict__ Wk,
                   const float* __restrict__ Wv,
                   const float* __restrict__ Wcomb,
                   const int*   __restrict__ prefix,
                   int*         __restrict__ out) {
  // ---- LDS ~52 KB -> 2 blocks/CU (wave-capped) ----
  __shared__ __align__(16) float sCE[S0*LDK];  // 47.5 KB: staging for K,V; final CE home
  __shared__ __align__(16) float sq[D];        // current q row
  __shared__ __align__(16) float sAtt[8*96];   // exp(score), pad rows 90..95 = 0
  __shared__ __align__(16) float sMh[D];       // q1 scratch, then normalized mh
  __shared__ float sSum[8];
  __shared__ int   sSlotNode[96];
  __shared__ unsigned long long sPacked[2];    // double-buffered argmax
  __shared__ int   sLast0;

  const int tid = threadIdx.x;
  const int b   = blockIdx.x;
  const float* encB = enc + (size_t)b*N*D;

  // ---- init ----
  if (tid < KL) out[(size_t)b*N + tid] = prefix[b*KL + tid];
  if (tid < 48) sAtt[(tid/6)*96 + 90 + (tid%6)] = 0.f;   // pad entries read by C
  if (tid == 0) {
    unsigned vis[4] = {0u,0u,0u,0u};
    const int* pr = prefix + b*KL;
    for (int j = 0; j < KL; ++j) { int n = pr[j]; vis[n>>5] |= 1u << (n&31); }
    int cnt = 0;
    for (int n = 0; n < N; ++n)
      if (!((vis[n>>5] >> (n&31)) & 1u)) sSlotNode[cnt++] = n;
    sLast0 = pr[KL-1];
    sPacked[0] = 0ull; sPacked[1] = 0ull;
  }
  __syncthreads();

  // ---- q1 = enc[last0] @ Wq_first -> sMh (scratch) ----
  if (tid < D) {
    const int last0 = sLast0;
    const float* er = encB + (size_t)last0*D;
    float a0=0,a1=0,a2=0,a3=0;
    #pragma unroll
    for (int d = 0; d < D; d += 4) {
      a0 += er[d]  *Wq_first[d*D     + tid];
      a1 += er[d+1]*Wq_first[(d+1)*D + tid];
      a2 += er[d+2]*Wq_first[(d+2)*D + tid];
      a3 += er[d+3]*Wq_first[(d+3)*D + tid];
    }
    sMh[tid] = (a0+a1)+(a2+a3);
  }
  __syncthreads();

  // ---- qP rows in REGISTERS: qp[ii] = q1[col] + (enc[row]@Wq_last)[col], row=grp+4*ii ----
  const int col = tid & 127;
  const int grp = tid >> 7;
  float qp[23];
  {
    int nd[23];
    #pragma unroll
    for (int ii = 0; ii < 23; ++ii) {
      int r = grp + 4*ii;
      nd[ii] = (r < S0) ? __builtin_amdgcn_readfirstlane(sSlotNode[r])
                        : ((r == S0) ? sLast0 : 0);
      qp[ii] = 0.f;
    }
    for (int dd = 0; dd < D; dd += 16) {
      float w[16];
      #pragma unroll
      for (int t = 0; t < 16; ++t) w[t] = Wq_last[(dd+t)*D + col];
      #pragma unroll
      for (int ii = 0; ii < 23; ++ii) {
        int r = grp + 4*ii;
        if (r <= S0) {
          const float* er = encB + (size_t)nd[ii]*D + dd;
          float a0=0,a1=0,a2=0,a3=0;
          #pragma unroll
          for (int t = 0; t < 16; t += 4) {
            a0 += er[t]*w[t];   a1 += er[t+1]*w[t+1];
            a2 += er[t+2]*w[t+2]; a3 += er[t+3]*w[t+3];
          }
          qp[ii] += (a0+a1)+(a2+a3);
        }
      }
    }
    const float q1c = sMh[col];
    #pragma unroll
    for (int ii = 0; ii < 23; ++ii) qp[ii] += q1c;
  }

  const int h = tid >> 6, l = tid & 63;

  // ---- K pass: stage all 90 rows, load per-lane fragments ----
  cc<23>(encB, Wk, false, 0, S0, sSlotNode, sCE, tid);
  __syncthreads();
  float4 ka0,ka1,ka2,ka3, kb0,kb1,kb2,kb3;
  {
    const float* p = &sCE[l*LDK + h*16];
    ka0 = *(const float4*)(p+0);  ka1 = *(const float4*)(p+4);
    ka2 = *(const float4*)(p+8);  ka3 = *(const float4*)(p+12);
  }
  if (l < 26) {
    const float* p = &sCE[(64+l)*LDK + h*16];
    kb0 = *(const float4*)(p+0);  kb1 = *(const float4*)(p+4);
    kb2 = *(const float4*)(p+8);  kb3 = *(const float4*)(p+12);
  } else {
    kb0=kb1=kb2=kb3 = make_float4(0.f,0.f,0.f,0.f);
  }
  __syncthreads();

  // ---- V pass: stage, load per-thread fragments ----
  const int cQuad = tid >> 4;   // 0..31 (output quad)
  const int cStrm = tid & 15;   // slot stream
  const int ch    = cQuad >> 2; // head
  cc<12>(encB, Wv, false,  0, 48, sSlotNode, sCE, tid);
  cc<12>(encB, Wv, false, 48, 42, sSlotNode, sCE, tid);
  __syncthreads();
  float4 v0,v1,v2,v3,v4,v5;
  v0 = *(const float4*)&sCE[(cStrm     )*LDK + cQuad*4];
  v1 = *(const float4*)&sCE[(cStrm + 16)*LDK + cQuad*4];
  v2 = *(const float4*)&sCE[(cStrm + 32)*LDK + cQuad*4];
  v3 = *(const float4*)&sCE[(cStrm + 48)*LDK + cQuad*4];
  v4 = *(const float4*)&sCE[(cStrm + 64)*LDK + cQuad*4];
  v5 = (cStrm < 10) ? *(const float4*)&sCE[(cStrm + 80)*LDK + cQuad*4]
                    : make_float4(0.f,0.f,0.f,0.f);
  __syncthreads();

  // ---- CE pass (final home, small RPT to cap pressure) + initial sq ----
  cc<6>(encB, Wcomb, true,  0, 24, sSlotNode, sCE, tid);
  cc<6>(encB, Wcomb, true, 24, 24, sSlotNode, sCE, tid);
  cc<6>(encB, Wcomb, true, 48, 24, sSlotNode, sCE, tid);
  cc<6>(encB, Wcomb, true, 72, 18, sSlotNode, sCE, tid);
  if (grp == 2) sq[col] = qp[22];     // row 90 = last0
  __syncthreads();

  // ---- decode: 90 steps, 4 barriers/step, all operands in regs/LDS ----
  const int di  = tid >> 2;    // phase D slot
  const int dkc = tid & 3;     // phase D k-chunk
  float visA = 0.f, visB = 0.f, visD = 0.f;

  for (int step = 0; step < STEPS; ++step) {
    const int p = step & 1;

    // B: scores vs register K; exp; per-head partition sum
    {
      if (tid == NT-1) sPacked[p] = 0ull;           // reset this step's argmax buffer
      const float4 q0 = *(const float4*)&sq[h*16 + 0];
      const float4 q1 = *(const float4*)&sq[h*16 + 4];
      const float4 q2 = *(const float4*)&sq[h*16 + 8];
      const float4 q3 = *(const float4*)&sq[h*16 + 12];
      float s0 = dot4(q0,ka0)+dot4(q1,ka1)+dot4(q2,ka2)+dot4(q3,ka3);
      float x0 = expf(s0*0.25f + visA);
      sAtt[h*96 + l] = x0;
      float x1 = 0.f;
      if (l < 26) {
        float s1 = dot4(q0,kb0)+dot4(q1,kb1)+dot4(q2,kb2)+dot4(q3,kb3);
        x1 = expf(s1*0.25f + visB);
        sAtt[h*96 + 64 + l] = x1;
      }
      float loc = x0 + x1;
      #pragma unroll
      for (int off = 32; off; off >>= 1) loc += __shfl_xor(loc, off);
      if (l == 0) sSum[h] = loc;
    }
    __syncthreads();

    // C: mh from register V, 16-lane butterfly, per-head normalize
    {
      float4 acc = make_float4(0.f,0.f,0.f,0.f);
      fma4(acc, sAtt[ch*96 + cStrm     ], v0);
      fma4(acc, sAtt[ch*96 + cStrm + 16], v1);
      fma4(acc, sAtt[ch*96 + cStrm + 32], v2);
      fma4(acc, sAtt[ch*96 + cStrm + 48], v3);
      fma4(acc, sAtt[ch*96 + cStrm + 64], v4);
      fma4(acc, sAtt[ch*96 + cStrm + 80], v5);      // v5=0 for cStrm>=10
      #pragma unroll
      for (int off = 1; off < 16; off <<= 1) {
        acc.x += __shfl_xor(acc.x, off);
        acc.y += __shfl_xor(acc.y, off);
        acc.z += __shfl_xor(acc.z, off);
        acc.w += __shfl_xor(acc.w, off);
      }
      if (cStrm == 0) {
        const float r = 1.0f / sSum[ch];
        float4 o; o.x=acc.x*r; o.y=acc.y*r; o.z=acc.z*r; o.w=acc.w*r;
        *(float4*)&sMh[cQuad*4] = o;
      }
    }
    __syncthreads();

    // D: sc[i] = mh . CE_lds[i]; argmax -> packed atomicMax
    if (tid < 384) {
      float a = 0.f;
      #pragma unroll
      for (int j = 0; j < 8; ++j) {
        const float4 ce = *(const float4*)&sCE[di*LDK + dkc*32 + j*4];
        const float4 mh = *(const float4*)&sMh[dkc*32 + j*4];
        a += dot4(ce, mh);
      }
      a += __shfl_xor(a, 1);
      a += __shfl_xor(a, 2);
      float val = (di < S0) ? a + visD : -INFINITY;
      int   idx = (di < S0) ? di : 127;
      #pragma unroll
      for (int off = 32; off; off >>= 1) {
        float ov = __shfl_xor(val, off);
        int   oi = __shfl_xor(idx, off);
        if (ov > val || (ov == val && oi < idx)) { val = ov; idx = oi; }
      }
      if (l == 0) {
        unsigned s = __float_as_uint(val);
        s = (s & 0x80000000u) ? ~s : (s | 0x80000000u);
        unsigned long long pk = ((unsigned long long)s << 32)
                              | (unsigned long long)(unsigned)(127 - idx);
        atomicMax(&sPacked[p], pk);
      }
    }
    __syncthreads();

    // E: broadcast winner; write out; update vis; owners publish next q row
    {
      const unsigned long long u = sPacked[p];
      const int idx = __builtin_amdgcn_readfirstlane(127 - (int)(u & 0xFFull));
      if (tid == 0) out[(size_t)b*N + KL + step] = sSlotNode[idx];
      if (idx == l)      visA = -INFINITY;
      if (idx == l + 64) visB = -INFINITY;
      if (idx == di)     visD = -INFINITY;
      const int want = idx >> 2;            // 0..22, wave-uniform (SGPR)
      float qv = qp[0];
      #pragma unroll
      for (int ii = 1; ii < 23; ++ii) qv = (want == ii) ? qp[ii] : qv;
      if (grp == (idx & 3)) sq[col] = qv;
    }
    __syncthreads();
  }
}

extern "C" void kernel_launch(void* const* d_in, const int* in_sizes, int n_in,
                              void* d_out, int out_size, void* d_ws, size_t ws_size,
                              hipStream_t stream) {
  // inputs: 0 problems (unused), 1 encoded_nodes f32, 2 Wq_first, 3 Wq_last,
  //         4 Wk, 5 Wv, 6 Wcomb, 7 prefix i32
  const float* enc      = (const float*)d_in[1];
  const float* Wq_first = (const float*)d_in[2];
  const float* Wq_last  = (const float*)d_in[3];
  const float* Wk       = (const float*)d_in[4];
  const float* Wv       = (const float*)d_in[5];
  const float* Wcomb    = (const float*)d_in[6];
  const int*   prefix   = (const int*)d_in[7];
  const int batch = in_sizes[7] / KL;   // 2048
  policy_kernel<<<batch, NT, 0, stream>>>(enc, Wq_first, Wq_last, Wk, Wv, Wcomb,
                                          prefix, (int*)d_out);
}